// Round 1
// baseline (427.344 us; speedup 1.0000x reference)
//
#include <hip/hip_runtime.h>
#include <math.h>

// Round 1: kill the random global scatter.
//   Path A (fused, needs ~48.03 MiB workspace):
//     Z: zero per-row counters
//     C: bin 3.2M directed entries {col, val*scale} by destination row (atomicAdd cursors)
//     D: per row: zero 32KiB LDS row -> scatter bucket entries into LDS -> diag ->
//        stream row to global with coalesced float4 stores. Output written once, coalesced.
//   Path B (fallback if workspace too small): previous verified fill+scatter kernels.

// ---------------------------------------------------------------- fused path

__global__ __launch_bounds__(256) void zero_counts_kernel(int* __restrict__ counts, int d)
{
    int t = blockIdx.x * blockDim.x + threadIdx.x;
    if (t < d) counts[t] = 0;
}

__global__ __launch_bounds__(256) void bin_kernel(
    const int*   __restrict__ idx,     // [2, M] int32
    const float* __restrict__ vals,    // [M]
    float scale,
    int m,
    int cap,
    uint2* __restrict__ entries,       // [D, cap] {col, f32 bits}
    int*   __restrict__ counts)        // [D]
{
    int k = blockIdx.x * blockDim.x + threadIdx.x;
    if (k >= m) return;
    int i = idx[k];
    int j = idx[m + k];
    unsigned vb = __float_as_uint(vals[k] * scale);

    int p1 = atomicAdd(&counts[i], 1);
    if (p1 < cap) entries[(long long)i * cap + p1] = make_uint2((unsigned)j, vb);
    int p2 = atomicAdd(&counts[j], 1);
    if (p2 < cap) entries[(long long)j * cap + p2] = make_uint2((unsigned)i, vb);
}

__global__ __launch_bounds__(256) void fused_rows_kernel(
    float* __restrict__ out,
    const float* __restrict__ h_local,
    const uint2* __restrict__ entries,
    const int*   __restrict__ counts,
    int cap,
    int logd,
    int rows_per_block)
{
    __shared__ float srow[8192];                    // 32 KiB: one full output row
    const int d  = 1 << logd;
    const int n4 = d >> 2;
    float4* s4 = reinterpret_cast<float4*>(srow);

    int r0 = blockIdx.x * rows_per_block;
    for (int rr = 0; rr < rows_per_block; ++rr) {
        int r = r0 + rr;

        // 1) zero the LDS row
        const float4 z = make_float4(0.f, 0.f, 0.f, 0.f);
        for (int c = threadIdx.x; c < n4; c += blockDim.x) s4[c] = z;
        __syncthreads();

        // 2) scatter this row's entries into LDS (no global RMW)
        int cnt = counts[r];
        if (cnt > cap) cnt = cap;                   // overflow guard (never expected)
        const uint2* eb = entries + (long long)r * cap;
        for (int e = threadIdx.x; e < cnt; e += blockDim.x) {
            uint2 p = eb[e];
            srow[p.x] = __uint_as_float(p.y);
        }
        if (threadIdx.x == 0) srow[r] = h_local[r]; // diagonal
        __syncthreads();

        // 3) stream the finished row to global, coalesced float4
        float4* orow = reinterpret_cast<float4*>(out + ((long long)r << logd));
        for (int c = threadIdx.x; c < n4; c += blockDim.x) orow[c] = s4[c];
        __syncthreads();                            // srow reused next row
    }
}

// ---------------------------------------------------------------- fallback path

__global__ __launch_bounds__(256) void fill_diag_kernel(
    float* __restrict__ out,
    const float* __restrict__ h_local,
    int logd,
    long long n4)
{
    long long t = (long long)blockIdx.x * blockDim.x + threadIdx.x;
    if (t >= n4) return;
    long long b = t << 2;
    int d_mask = (1 << logd) - 1;
    int row  = (int)(b >> logd);
    int col0 = (int)(b & d_mask);

    float4 v = make_float4(0.f, 0.f, 0.f, 0.f);
    int dcol = row - col0;
    if (dcol >= 0 && dcol < 4) {
        float hv = h_local[row];
        v.x = (dcol == 0) ? hv : 0.f;
        v.y = (dcol == 1) ? hv : 0.f;
        v.z = (dcol == 2) ? hv : 0.f;
        v.w = (dcol == 3) ? hv : 0.f;
    }
    reinterpret_cast<float4*>(out)[t] = v;
}

__global__ __launch_bounds__(256) void scatter_kernel(
    float* __restrict__ out,
    const int* __restrict__ idx,
    const float* __restrict__ vals,
    float scale,
    int m,
    int logd)
{
    int k = blockIdx.x * blockDim.x + threadIdx.x;
    if (k >= m) return;
    int i = idx[k];
    int j = idx[m + k];
    float v = vals[k] * scale;
    out[((long long)i << logd) + j] = v;
    out[((long long)j << logd) + i] = v;
}

// ---------------------------------------------------------------- launch

extern "C" void kernel_launch(void* const* d_in, const int* in_sizes, int n_in,
                              void* d_out, int out_size, void* d_ws, size_t ws_size,
                              hipStream_t stream) {
    const float* h_local = (const float*)d_in[0];
    const float* V_int   = (const float*)d_in[1];
    const int*   idx     = (const int*)d_in[2];

    const int d = in_sizes[0];            // 8192
    const int m = in_sizes[1];            // 1,600,000

    int logd = 0;
    while ((1 << logd) < d) ++logd;

    const float iscale = (float)(1.0 - 0.2 / sqrt(log((double)d)));
    float* out = (float*)d_out;
    const int block = 256;

    // Workspace layout: [ counts: d*int ][ entries: d*cap*uint2 ]
    size_t counts_bytes = (size_t)d * sizeof(int);
    long long cap = 0;
    if (ws_size > counts_bytes + 64) {
        cap = (long long)((ws_size - counts_bytes) / ((size_t)d * sizeof(uint2)));
        if (cap > 1024) cap = 1024;
    }
    const bool pow2  = ((1 << logd) == d);
    const bool fused = pow2 && d <= 8192 && cap >= 576 && d_ws != nullptr;

    if (fused) {
        int*   counts  = (int*)d_ws;
        uint2* entries = (uint2*)((char*)d_ws + counts_bytes);

        const int grid_z = (d + block - 1) / block;
        zero_counts_kernel<<<grid_z, block, 0, stream>>>(counts, d);

        const int grid_c = (m + block - 1) / block;
        bin_kernel<<<grid_c, block, 0, stream>>>(idx, V_int, iscale, m, (int)cap,
                                                 entries, counts);

        const int rows_per_block = 4;
        const int grid_d = d / rows_per_block;      // 2048 blocks
        fused_rows_kernel<<<grid_d, block, 0, stream>>>(out, h_local, entries, counts,
                                                        (int)cap, logd, rows_per_block);
    } else {
        const long long n4 = ((long long)d * d) >> 2;
        const long long grid_fill = (n4 + block - 1) / block;
        fill_diag_kernel<<<(dim3)(unsigned)grid_fill, block, 0, stream>>>(out, h_local, logd, n4);

        const int grid_sc = (m + block - 1) / block;
        scatter_kernel<<<grid_sc, block, 0, stream>>>(out, idx, V_int, iscale, m, logd);
    }
}

// Round 2
// 417.312 us; speedup vs baseline: 1.0240x; 1.0240x over previous
//
#include <hip/hip_runtime.h>
#include <math.h>

// Round 2: row-binning WITHOUT workspace (the 1 GiB ws re-poison cost 184 us/iter).
// The output buffer doubles as bin storage:
//   row r layout during build:  [0]=count (int bits), [2+2p]=col (uint bits), [3+2p]=val
//   expected count/row ~391, max ~500  <<  capacity (d-2)/2 = 4095.
// K1 init:  out[r][0] = 0
// K2 bin:   atomicAdd cursor at out[row][0]; pack {col, val*scale} uint2 at out[row][2+2p].
//           Hot region = first ~3.2 KB of each row (~26 MB) -> L2/L3-resident.
// K3 rows:  per block: zero 32KiB LDS row -> scatter packed entries into LDS -> diag ->
//           stream row to global once, coalesced float4. Read-before-overwrite ordered
//           by __syncthreads inside the block.

// ---------------------------------------------------------------- fused path

__global__ __launch_bounds__(256) void init_counts_kernel(
    float* __restrict__ out, int d, int logd)
{
    int r = blockIdx.x * blockDim.x + threadIdx.x;
    if (r < d) {
        reinterpret_cast<int*>(out)[(long long)r << logd] = 0;
    }
}

__global__ __launch_bounds__(256) void bin_kernel(
    float* __restrict__ out,
    const int*   __restrict__ idx,     // [2, M] int32
    const float* __restrict__ vals,    // [M]
    float scale,
    int m,
    int logd,
    int cap)                           // max entries per row
{
    int k = blockIdx.x * blockDim.x + threadIdx.x;
    if (k >= m) return;
    int i = idx[k];
    int j = idx[m + k];
    unsigned vb = __float_as_uint(vals[k] * scale);

    int* cnt_i = reinterpret_cast<int*>(out) + ((long long)i << logd);
    int* cnt_j = reinterpret_cast<int*>(out) + ((long long)j << logd);

    int p1 = atomicAdd(cnt_i, 1);
    if (p1 < cap) {
        uint2* dst = reinterpret_cast<uint2*>(out + ((long long)i << logd) + 2 + 2 * p1);
        *dst = make_uint2((unsigned)j, vb);
    }
    int p2 = atomicAdd(cnt_j, 1);
    if (p2 < cap) {
        uint2* dst = reinterpret_cast<uint2*>(out + ((long long)j << logd) + 2 + 2 * p2);
        *dst = make_uint2((unsigned)i, vb);
    }
}

__global__ __launch_bounds__(256) void rows_kernel(
    float* __restrict__ out,
    const float* __restrict__ h_local,
    int logd,
    int cap)
{
    __shared__ float srow[8192];                    // 32 KiB: one full output row
    const int d  = 1 << logd;
    const int n4 = d >> 2;
    float4* s4 = reinterpret_cast<float4*>(srow);

    const int r = blockIdx.x;
    float* grow = out + ((long long)r << logd);

    // 1) zero the LDS row
    const float4 z = make_float4(0.f, 0.f, 0.f, 0.f);
    for (int c = threadIdx.x; c < n4; c += blockDim.x) s4[c] = z;
    __syncthreads();

    // 2) scatter this row's packed entries into LDS (coalesced global reads)
    int cnt = reinterpret_cast<const int*>(grow)[0];   // same-address broadcast load
    if (cnt > cap) cnt = cap;
    const uint2* eb = reinterpret_cast<const uint2*>(grow + 2);
    for (int e = threadIdx.x; e < cnt; e += blockDim.x) {
        uint2 p = eb[e];
        srow[p.x] = __uint_as_float(p.y);
    }
    if (threadIdx.x == 0) srow[r] = h_local[r];        // diagonal
    __syncthreads();                                   // all reads of grow done

    // 3) stream the finished row to global, coalesced float4 (overwrites packed region)
    for (int c = threadIdx.x; c < n4; c += blockDim.x) {
        reinterpret_cast<float4*>(grow)[c] = s4[c];
    }
}

// ---------------------------------------------------------------- fallback path

__global__ __launch_bounds__(256) void fill_diag_kernel(
    float* __restrict__ out,
    const float* __restrict__ h_local,
    int d,
    long long n)
{
    long long t = (long long)blockIdx.x * blockDim.x + threadIdx.x;
    if (t >= n) return;
    long long row = t / d;
    long long col = t - row * d;
    out[t] = (row == col) ? h_local[row] : 0.f;
}

__global__ __launch_bounds__(256) void scatter_kernel(
    float* __restrict__ out,
    const int* __restrict__ idx,
    const float* __restrict__ vals,
    float scale,
    int m,
    int d)
{
    int k = blockIdx.x * blockDim.x + threadIdx.x;
    if (k >= m) return;
    int i = idx[k];
    int j = idx[m + k];
    float v = vals[k] * scale;
    out[(long long)i * d + j] = v;
    out[(long long)j * d + i] = v;
}

// ---------------------------------------------------------------- launch

extern "C" void kernel_launch(void* const* d_in, const int* in_sizes, int n_in,
                              void* d_out, int out_size, void* d_ws, size_t ws_size,
                              hipStream_t stream) {
    const float* h_local = (const float*)d_in[0];
    const float* V_int   = (const float*)d_in[1];
    const int*   idx     = (const int*)d_in[2];

    const int d = in_sizes[0];            // 8192
    const int m = in_sizes[1];            // 1,600,000

    int logd = 0;
    while ((1 << logd) < d) ++logd;
    const bool pow2 = ((1 << logd) == d);

    const float iscale = (float)(1.0 - 0.2 / sqrt(log((double)d)));
    float* out = (float*)d_out;
    const int block = 256;

    // Fused path needs: pow2 d, row fits in 32 KiB LDS, packed capacity comfortably
    // above the expected max bucket (~500 for D=8192, M=1.6M).
    const int cap = (d - 2) / 2;
    const bool fused = pow2 && d >= 1024 && d <= 8192 &&
                       ((long long)m * 2 / d) < (long long)cap / 2;

    if (fused) {
        const int grid_i = (d + block - 1) / block;
        init_counts_kernel<<<grid_i, block, 0, stream>>>(out, d, logd);

        const int grid_b = (m + block - 1) / block;
        bin_kernel<<<grid_b, block, 0, stream>>>(out, idx, V_int, iscale, m, logd, cap);

        rows_kernel<<<d, block, 0, stream>>>(out, h_local, logd, cap);
    } else {
        const long long n = (long long)d * d;
        const long long grid_fill = (n + block - 1) / block;
        fill_diag_kernel<<<(dim3)(unsigned)grid_fill, block, 0, stream>>>(out, h_local, d, n);

        const int grid_sc = (m + block - 1) / block;
        scatter_kernel<<<grid_sc, block, 0, stream>>>(out, idx, V_int, iscale, m, d);
    }
}